// Round 13
// baseline (1910.524 us; speedup 1.0000x reference)
//
#include <hip/hip_runtime.h>
#include <hip/hip_bf16.h>

// ---------------------------------------------------------------------------
// 2-layer GRU + ReLU + Linear as two sequential kernels, 256 blocks x 512 thr.
// Allocator law (R1-R12): arch-VGPR cap = 65536/blockDim (demand-tracking
// below the cap, AGPR-overflow with ~6cyc/dot2 move tax above it). R12 proved
// tax-free at 256 thr but died of 1 wave/SIMD latency exposure. This round:
// 512 threads (2 waves/SIMD latency hiding) AND per-kernel demand < 128:
//   K1: wi0(12)+wh0(48) = 60 h2 + ~35 working  ~= 95 regs
//   K2: wi1(48)+wh1(48) = 96 h2 + ~30 working  ~= 126 regs
// Per step: thread owns rows {q,128+q,256+q} (q=tid>>2), k-quarter ql=tid&3;
// 2-round butterfly reduce; E in ql==0 lanes; state double-buffered in LDS;
// ONE light (lgkm-only) barrier per step (global stores drain lazily);
// h1/out stores batched x16 via LDS rings; K2 output reduce deferred to flush.
// ---------------------------------------------------------------------------

typedef _Float16 h2 __attribute__((ext_vector_type(2)));

__device__ __forceinline__ float dot2f(h2 a, h2 b, float c) {
#if __has_builtin(__builtin_amdgcn_fdot2)
  return __builtin_amdgcn_fdot2(a, b, c, false);
#else
  return c + (float)a[0] * (float)b[0] + (float)a[1] * (float)b[1];
#endif
}
__device__ __forceinline__ h2 pack2(float x, float y) {
  h2 r; r[0] = (_Float16)x; r[1] = (_Float16)y; return r;
}
__device__ __forceinline__ float sigm(float x) { return 1.f / (1.f + __expf(-x)); }
__device__ __forceinline__ float tanh_f(float x) {
  x = fminf(fmaxf(x, -15.f), 15.f);
  float e = __expf(2.f * x);
  return (e - 1.f) / (e + 1.f);
}
__device__ __forceinline__ void load_pack8(const float* p, h2* w) {
  float4 a = ((const float4*)p)[0], b = ((const float4*)p)[1];
  w[0] = pack2(a.x, a.y); w[1] = pack2(a.z, a.w);
  w[2] = pack2(b.x, b.y); w[3] = pack2(b.z, b.w);
}
// Light barrier: waits LDS ops only (global stores keep draining lazily).
__device__ __forceinline__ void lbar() {
  asm volatile("s_waitcnt lgkmcnt(0)\ns_barrier" ::: "memory");
}

#define SEQ 1200
#define HID 128
#define INSZ 32

// 4 dot2 of a h2[4] weight group against a uint4 (8 f16) state fragment
#define DOTU4(W, U, ACC)                                            \
  ACC = dot2f((W)[0], __builtin_bit_cast(h2, (U).x), ACC);          \
  ACC = dot2f((W)[1], __builtin_bit_cast(h2, (U).y), ACC);          \
  ACC = dot2f((W)[2], __builtin_bit_cast(h2, (U).z), ACC);          \
  ACC = dot2f((W)[3], __builtin_bit_cast(h2, (U).w), ACC);

// =================== Kernel 1: layer-1 GRU, h1 -> scratch ===================
__global__ __launch_bounds__(512) void gru_l1(
    const float* __restrict__ x,
    const float* __restrict__ Wih0, const float* __restrict__ Whh0,
    const float* __restrict__ bih0, const float* __restrict__ bhh0,
    unsigned short* __restrict__ h1g)
{
  const int tid = threadIdx.x, b = blockIdx.x;
  const int q = tid >> 2, ql = tid & 3;   // unit q (0..127), k-quarter ql

  __shared__ __align__(16) _Float16 s0h[2][HID];        // h1 state, dbl-buf
  __shared__ __align__(16) _Float16 xh[2][INSZ];        // x row, dbl-buf
  __shared__ __align__(16) _Float16 ring[2][16][HID];   // h1 out ring (8KB)

  // per-thread weights: rows {q, 128+q, 256+q}, k-quarter ql. 60 h2 regs.
  h2 wi0[3][4];    // W_ih0 row quarter (8 f16)
  h2 wh0[3][16];   // W_hh0 row quarter (32 f16)
#pragma unroll
  for (int g = 0; g < 3; ++g) {
    const int row = g * HID + q;
    load_pack8(Wih0 + (size_t)row * INSZ + ql * 8, wi0[g]);
#pragma unroll
    for (int c = 0; c < 4; ++c)
      load_pack8(Whh0 + (size_t)row * HID + ql * 32 + c * 8, &wh0[g][c * 4]);
  }
  const float bA = bih0[q] + bhh0[q];
  const float bB = bih0[HID + q] + bhh0[HID + q];
  const float bC = bih0[2 * HID + q];
  const float bD = bhh0[2 * HID + q];

  float hprev = 0.f;
  if (tid < 64) ((float*)s0h[0])[tid] = 0.f;
  const float2* xsrc = (const float2*)x + (size_t)b * SEQ * (INSZ / 2);
  if (tid < 16) { float2 v = xsrc[tid]; ((h2*)xh[0])[tid] = pack2(v.x, v.y); }
  __syncthreads();

  unsigned short* hout = h1g + (size_t)b * SEQ * HID;

  for (int t = 0; t < SEQ; ++t) {
    const int rb = t & 1, wb = rb ^ 1;
    // prefetch x_{t+1} on ql==1 lanes of units 0..15 (E lanes are ql==0)
    const bool ldx = (ql == 1) && (q < 16);
    float2 xn;
    if (ldx) xn = xsrc[(size_t)((t + 1 < SEQ) ? t + 1 : SEQ - 1) * 16 + q];

    const uint4 xq = ((const uint4*)xh[rb])[ql];
    const uint4* sp = (const uint4*)s0h[rb];
    float a0 = 0.f, a1 = 0.f, a2 = 0.f, a3 = 0.f;
    DOTU4(wi0[0], xq, a0)
    DOTU4(wi0[1], xq, a1)
    DOTU4(wi0[2], xq, a2)
#pragma unroll
    for (int c = 0; c < 4; ++c) {   // h-part, chunked state reads
      const uint4 s = sp[ql * 4 + c];
      DOTU4(&wh0[0][c * 4], s, a0)
      DOTU4(&wh0[1][c * 4], s, a1)
      DOTU4(&wh0[2][c * 4], s, a3)
    }
    a0 += __shfl_xor(a0, 1, 64); a0 += __shfl_xor(a0, 2, 64);
    a1 += __shfl_xor(a1, 1, 64); a1 += __shfl_xor(a1, 2, 64);
    a2 += __shfl_xor(a2, 1, 64); a2 += __shfl_xor(a2, 2, 64);
    a3 += __shfl_xor(a3, 1, 64); a3 += __shfl_xor(a3, 2, 64);

    if (ql == 0) {
      float r = sigm(a0 + bA);
      float z = sigm(a1 + bB);
      float n = tanh_f(a2 + bC + r * (a3 + bD));
      float h = (1.f - z) * n + z * hprev;
      hprev = h;
      const _Float16 hf = (_Float16)h;
      s0h[wb][q] = hf;
      ring[(t >> 4) & 1][t & 15][q] = hf;
    } else if (ldx) {
      ((h2*)xh[wb])[q] = pack2(xn.x, xn.y);
    }
    lbar();
    if ((t & 15) == 15) {   // flush 16 rows (4KB) coalesced; drains lazily
      const uint2 v = ((const uint2*)ring[(t >> 4) & 1])[tid];
      ((uint2*)(hout + (size_t)(t - 15) * HID))[tid] = v;
    }
  }
}

// ============ Kernel 2: layer-2 GRU + ReLU + Linear head -> out ============
__global__ __launch_bounds__(512) void gru_l2(
    const unsigned short* __restrict__ h1g,
    const float* __restrict__ Wih1, const float* __restrict__ Whh1,
    const float* __restrict__ bih1, const float* __restrict__ bhh1,
    const float* __restrict__ Wlin, const float* __restrict__ blin,
    float* __restrict__ out)
{
  const int tid = threadIdx.x, b = blockIdx.x;
  const int q = tid >> 2, ql = tid & 3;

  __shared__ __align__(16) _Float16 s1h[2][HID];   // h2 state, dbl-buf
  __shared__ __align__(16) _Float16 hb[2][HID];    // staged h1_t, dbl-buf
  __shared__ float pring[2][16][HID];              // ReLU(h)*w partials (16KB)

  // per-thread weights: rows {q, 128+q, 256+q}, k-quarter ql. 96 h2 regs.
  h2 wi1[3][16];   // W_ih1 row quarter (32 f16)
  h2 wh1[3][16];   // W_hh1 row quarter
#pragma unroll
  for (int g = 0; g < 3; ++g) {
    const int row = g * HID + q;
#pragma unroll
    for (int c = 0; c < 4; ++c) {
      load_pack8(Wih1 + (size_t)row * HID + ql * 32 + c * 8, &wi1[g][c * 4]);
      load_pack8(Whh1 + (size_t)row * HID + ql * 32 + c * 8, &wh1[g][c * 4]);
    }
  }
  const float bA = bih1[q] + bhh1[q];
  const float bB = bih1[HID + q] + bhh1[HID + q];
  const float bC = bih1[2 * HID + q];
  const float bD = bhh1[2 * HID + q];
  const float wl = Wlin[q];
  const float blv = blin[0];

  float hprev = 0.f;
  if (tid < 64) ((float*)s1h[0])[tid] = 0.f;
  const uint4* hsrc = (const uint4*)(h1g + (size_t)b * SEQ * HID);  // 16 / t
  if (tid < 16) ((uint4*)hb[0])[tid] = hsrc[tid];
  __syncthreads();

  float* outp = out + (size_t)b * SEQ;

  for (int t = 0; t < SEQ; ++t) {
    const int rb = t & 1, wb = rb ^ 1;
    // prefetch h1_{t+1} on ql==1 lanes of units 0..15
    const bool ldh = (ql == 1) && (q < 16);
    uint4 hn;
    if (ldh) hn = hsrc[(size_t)((t + 1 < SEQ) ? t + 1 : SEQ - 1) * 16 + q];

    const uint4* hp = (const uint4*)hb[rb];
    const uint4* sp = (const uint4*)s1h[rb];
    float a0 = 0.f, a1 = 0.f, a2 = 0.f, a3 = 0.f;
#pragma unroll
    for (int c = 0; c < 4; ++c) {   // chunked: 2 live state uint4 at a time
      const uint4 hu = hp[ql * 4 + c];
      const uint4 su = sp[ql * 4 + c];
      DOTU4(&wi1[0][c * 4], hu, a0) DOTU4(&wh1[0][c * 4], su, a0)
      DOTU4(&wi1[1][c * 4], hu, a1) DOTU4(&wh1[1][c * 4], su, a1)
      DOTU4(&wi1[2][c * 4], hu, a2) DOTU4(&wh1[2][c * 4], su, a3)
    }
    a0 += __shfl_xor(a0, 1, 64); a0 += __shfl_xor(a0, 2, 64);
    a1 += __shfl_xor(a1, 1, 64); a1 += __shfl_xor(a1, 2, 64);
    a2 += __shfl_xor(a2, 1, 64); a2 += __shfl_xor(a2, 2, 64);
    a3 += __shfl_xor(a3, 1, 64); a3 += __shfl_xor(a3, 2, 64);

    if (ql == 0) {
      float r = sigm(a0 + bA);
      float z = sigm(a1 + bB);
      float n = tanh_f(a2 + bC + r * (a3 + bD));
      float h = (1.f - z) * n + z * hprev;
      hprev = h;
      s1h[wb][q] = (_Float16)h;
      pring[(t >> 4) & 1][t & 15][q] = fmaxf(h, 0.f) * wl;   // deferred reduce
    } else if (ldh) {
      ((uint4*)hb[wb])[q] = hn;
    }
    lbar();
    if ((t & 15) == 15 && tid < 64) {   // flush: 16 outputs, wave 0 only
      const int o = tid >> 2, qp = tid & 3;
      const float* pr = &pring[(t >> 4) & 1][o][qp * 32];
      float s0 = 0.f, s1 = 0.f;
#pragma unroll
      for (int j = 0; j < 16; ++j) {    // lane-staggered: conflict-free banks
        s0 += pr[(2 * j + tid) & 31];
        s1 += pr[(2 * j + 1 + tid) & 31];
      }
      float s = s0 + s1;
      s += __shfl_xor(s, 1, 64);
      s += __shfl_xor(s, 2, 64);
      if (qp == 0) outp[t - 15 + o] = s + blv;
    }
  }
}

extern "C" void kernel_launch(void* const* d_in, const int* in_sizes, int n_in,
                              void* d_out, int out_size, void* d_ws, size_t ws_size,
                              hipStream_t stream) {
  const float* x    = (const float*)d_in[0];
  const float* Wih0 = (const float*)d_in[1];
  const float* Whh0 = (const float*)d_in[2];
  const float* bih0 = (const float*)d_in[3];
  const float* bhh0 = (const float*)d_in[4];
  const float* Wih1 = (const float*)d_in[5];
  const float* Whh1 = (const float*)d_in[6];
  const float* bih1 = (const float*)d_in[7];
  const float* bhh1 = (const float*)d_in[8];
  const float* Wlin = (const float*)d_in[9];
  const float* blin = (const float*)d_in[10];
  float* outp = (float*)d_out;

  const int Bn = in_sizes[0] / (SEQ * INSZ);   // 256
  unsigned short* h1g = (unsigned short*)d_ws; // B*SEQ*HID f16 = 78.6 MB

  hipLaunchKernelGGL(gru_l1, dim3(Bn), dim3(512), 0, stream,
                     x, Wih0, Whh0, bih0, bhh0, h1g);
  hipLaunchKernelGGL(gru_l2, dim3(Bn), dim3(512), 0, stream,
                     h1g, Wih1, Whh1, bih1, bhh1, Wlin, blin, outp);
}